// Round 2
// baseline (258.935 us; speedup 1.0000x reference)
//
#include <hip/hip_runtime.h>
#include <math.h>

#define EPS 1e-7f

constexpr int B = 16, L = 1024, D = 256, P = 20;
constexpr int LD = L * D;     // 262144
constexpr int DD = D * D;     // 65536

// ---------------------------------------------------------------------------
// ws layout (floats):
//   n1    : [B*L]     @ 0        (16384)
//   invn2 : [B*L]     @ 16384    (16384)
//   t     : [B*D]     @ 32768    (4096)    -- zeroed, atomic-accumulated
//   G     : [B*D*D]   @ 36864    (1048576) -- zeroed, atomic-accumulated
//   mav   : [B*L*D]   @ 1085440  (4194304)
// ---------------------------------------------------------------------------

// K1: per-row L2 norms. n1 stored plain, n2 stored as reciprocal.
__global__ __launch_bounds__(256) void k_norms(const float* __restrict__ s1,
                                               const float* __restrict__ s2,
                                               float* __restrict__ n1,
                                               float* __restrict__ invn2) {
    int tid  = threadIdx.x;
    int lane = tid & 63, w = tid >> 6;
    int row  = blockIdx.x * 4 + w;            // 0..32767
    int r    = (row < B * L) ? row : row - B * L;
    const float* src = (row < B * L) ? s1 : s2;
    float4 v = *(const float4*)(src + (size_t)r * D + lane * 4);
    float s = v.x * v.x + v.y * v.y + v.z * v.z + v.w * v.w;
#pragma unroll
    for (int o = 32; o; o >>= 1) s += __shfl_down(s, o);
    if (lane == 0) {
        float n = sqrtf(fmaxf(s, EPS));
        if (row < B * L) n1[r] = n;
        else             invn2[r] = 1.0f / n;
    }
}

// K2: t[b,d] = sum_m s2[b,m,d] * invn2[b,m].  Grid: 16 b x 32 m-chunks.
__global__ __launch_bounds__(256) void k_t(const float* __restrict__ s2,
                                           const float* __restrict__ invn2,
                                           float* __restrict__ t) {
    int b  = blockIdx.x >> 5;
    int mc = blockIdx.x & 31;                 // 32 m per chunk
    int d  = threadIdx.x;
    const float* sp = s2 + (size_t)b * LD + (size_t)mc * 32 * D + d;
    const float* wp = invn2 + b * L + mc * 32;
    float acc = 0.f;
#pragma unroll 4
    for (int m = 0; m < 32; ++m) acc += sp[(size_t)m * D] * wp[m];
    atomicAdd(&t[b * D + d], acc);
}

// K3: G[b] += S2_chunk^T diag(invn2) S2_chunk.  64x64 tile, 4x4/thread,
// K(m)-split x8 with atomicAdd.  Grid: 16 b x (4 ti x 4 tj x 8 kc) = 2048.
__global__ __launch_bounds__(256) void k_gram(const float* __restrict__ s2,
                                              const float* __restrict__ invn2,
                                              float* __restrict__ G) {
    __shared__ float As[16][68];
    __shared__ float Bs[16][68];
    int tid = threadIdx.x;
    int b   = blockIdx.x >> 7;
    int rem = blockIdx.x & 127;
    int ti  = rem >> 5;
    int tj  = (rem >> 3) & 3;
    int kc  = rem & 7;
    int tx  = tid & 15, ty = tid >> 4;
    int m0  = kc * 128;

    float acc[4][4];
#pragma unroll
    for (int i = 0; i < 4; ++i)
#pragma unroll
        for (int j = 0; j < 4; ++j) acc[i][j] = 0.f;

    int sk = tid >> 4, sc = tid & 15;         // staging coords
    for (int mc = 0; mc < 8; ++mc) {
        int mbase = m0 + mc * 16;
        __syncthreads();
        {
            int r = mbase + sk;
            float w = invn2[b * L + r];
            const float* base = s2 + (size_t)b * LD + (size_t)r * D;
            float4 va = *(const float4*)(base + ti * 64 + sc * 4);
            float4 vb = *(const float4*)(base + tj * 64 + sc * 4);
            float4 sa; sa.x = va.x * w; sa.y = va.y * w; sa.z = va.z * w; sa.w = va.w * w;
            *(float4*)&As[sk][sc * 4] = sa;
            *(float4*)&Bs[sk][sc * 4] = vb;
        }
        __syncthreads();
#pragma unroll
        for (int k = 0; k < 16; ++k) {
            float4 a4 = *(const float4*)&As[k][ty * 4];
            float4 b4 = *(const float4*)&Bs[k][tx * 4];
            float a[4] = {a4.x, a4.y, a4.z, a4.w};
            float bb[4] = {b4.x, b4.y, b4.z, b4.w};
#pragma unroll
            for (int i = 0; i < 4; ++i)
#pragma unroll
                for (int j = 0; j < 4; ++j) acc[i][j] += a[i] * bb[j];
        }
    }
    float* gp = G + (size_t)b * DD + (size_t)(ti * 64 + ty * 4) * D + tj * 64 + tx * 4;
#pragma unroll
    for (int i = 0; i < 4; ++i)
#pragma unroll
        for (int j = 0; j < 4; ++j)
            atomicAdd(gp + (size_t)i * D + j, acc[i][j]);
}

// K4: u = s1 @ G (per batch), fused U = s1 . t accumulation, epilogue writes
// mav = u / (U + EPS*n1).  64x64 tiles, 4x4/thread.  Grid: 16 b x 16 lt x 4 nt.
__global__ __launch_bounds__(256) void k_mav(const float* __restrict__ s1,
                                             const float* __restrict__ G,
                                             const float* __restrict__ t,
                                             const float* __restrict__ n1,
                                             float* __restrict__ mav) {
    __shared__ float As[16][68];   // transposed s1 chunk: As[k][l]
    __shared__ float Bs[16][68];   // G chunk: Bs[k][n]
    __shared__ float ts[16];
    int tid = threadIdx.x;
    int b   = blockIdx.x >> 6;
    int rem = blockIdx.x & 63;
    int lt  = rem >> 2, nt = rem & 3;
    int l0  = lt * 64, n0 = nt * 64;
    int tx  = tid & 15, ty = tid >> 4;

    float acc[4][4];
    float Ua[4];
#pragma unroll
    for (int i = 0; i < 4; ++i) {
        Ua[i] = 0.f;
#pragma unroll
        for (int j = 0; j < 4; ++j) acc[i][j] = 0.f;
    }

    int c4 = tid & 3, lrow = tid >> 2;        // A-staging coords (lrow 0..63)
    int sk = tid >> 4, sc = tid & 15;         // B-staging coords
    for (int kc = 0; kc < 16; ++kc) {
        __syncthreads();
        {
            // stage A (transpose): s1[l0+l][kc*16 + c4*4 .. +3] -> As[k][l]
            float4 v = *(const float4*)(s1 + (size_t)b * LD + (size_t)(l0 + lrow) * D +
                                        kc * 16 + c4 * 4);
            As[c4 * 4 + 0][lrow] = v.x;
            As[c4 * 4 + 1][lrow] = v.y;
            As[c4 * 4 + 2][lrow] = v.z;
            As[c4 * 4 + 3][lrow] = v.w;
            // stage B: G[kc*16+sk][n0 + sc*4]
            float4 g = *(const float4*)(G + (size_t)b * DD + (size_t)(kc * 16 + sk) * D +
                                        n0 + sc * 4);
            *(float4*)&Bs[sk][sc * 4] = g;
            if (tid < 16) ts[tid] = t[b * D + kc * 16 + tid];
        }
        __syncthreads();
#pragma unroll
        for (int k = 0; k < 16; ++k) {
            float4 a4 = *(const float4*)&As[k][ty * 4];
            float4 b4 = *(const float4*)&Bs[k][tx * 4];
            float tk = ts[k];
            float a[4] = {a4.x, a4.y, a4.z, a4.w};
            float bb[4] = {b4.x, b4.y, b4.z, b4.w};
#pragma unroll
            for (int i = 0; i < 4; ++i) {
                Ua[i] += a[i] * tk;
#pragma unroll
                for (int j = 0; j < 4; ++j) acc[i][j] += a[i] * bb[j];
            }
        }
    }
#pragma unroll
    for (int i = 0; i < 4; ++i) {
        int l = l0 + ty * 4 + i;
        float n1v = n1[b * L + l];
        float inv = 1.0f / (Ua[i] + EPS * n1v);
        float4 o;
        o.x = acc[i][0] * inv; o.y = acc[i][1] * inv;
        o.z = acc[i][2] * inv; o.w = acc[i][3] * inv;
        *(float4*)(mav + (size_t)(b * L + l) * D + n0 + tx * 4) = o;
    }
}

// K5: out[b,l,p] = num / nv1 / nv2 over k2 = kernel^2.  One wave per row.
__global__ __launch_bounds__(256) void k_out(const float* __restrict__ s1,
                                             const float* __restrict__ mav,
                                             const float* __restrict__ kern,
                                             float* __restrict__ out) {
    __shared__ float k2s[P * D];   // 20 KB
    int tid = threadIdx.x;
#pragma unroll
    for (int p = 0; p < P; ++p) {
        float v = kern[p * D + tid];
        k2s[p * D + tid] = v * v;
    }
    __syncthreads();

    int w = tid >> 6, lane = tid & 63;
    int row = blockIdx.x * 4 + w;             // 0..16383
    int dg = lane & 15, ps = lane >> 4;

    const float* s1p = s1 + (size_t)row * D + dg * 4;
    const float* mvp = mav + (size_t)row * D + dg * 4;
    float4 sm[4], ss[4], mm[4];
#pragma unroll
    for (int j = 0; j < 4; ++j) {
        float4 sv = *(const float4*)(s1p + j * 64);
        float4 mv = *(const float4*)(mvp + j * 64);
        sm[j].x = sv.x * mv.x; sm[j].y = sv.y * mv.y; sm[j].z = sv.z * mv.z; sm[j].w = sv.w * mv.w;
        ss[j].x = sv.x * sv.x; ss[j].y = sv.y * sv.y; ss[j].z = sv.z * sv.z; ss[j].w = sv.w * sv.w;
        mm[j].x = mv.x * mv.x; mm[j].y = mv.y * mv.y; mm[j].z = mv.z * mv.z; mm[j].w = mv.w * mv.w;
    }
#pragma unroll
    for (int tI = 0; tI < 5; ++tI) {
        int p = ps + tI * 4;                  // 0..19
        float na = 0.f, nb = 0.f, nc = 0.f;
#pragma unroll
        for (int j = 0; j < 4; ++j) {
            float4 kv = *(const float4*)&k2s[p * D + j * 64 + dg * 4];
            na += sm[j].x * kv.x + sm[j].y * kv.y + sm[j].z * kv.z + sm[j].w * kv.w;
            nb += ss[j].x * kv.x + ss[j].y * kv.y + ss[j].z * kv.z + ss[j].w * kv.w;
            nc += mm[j].x * kv.x + mm[j].y * kv.y + mm[j].z * kv.z + mm[j].w * kv.w;
        }
#pragma unroll
        for (int o = 8; o; o >>= 1) {
            na += __shfl_down(na, o, 16);
            nb += __shfl_down(nb, o, 16);
            nc += __shfl_down(nc, o, 16);
        }
        if (dg == 0) {
            float d1 = sqrtf(fmaxf(nb, EPS));
            float d2 = sqrtf(fmaxf(nc, EPS));
            out[row * P + p] = na / d1 / d2;
        }
    }
}

extern "C" void kernel_launch(void* const* d_in, const int* in_sizes, int n_in,
                              void* d_out, int out_size, void* d_ws, size_t ws_size,
                              hipStream_t stream) {
    const float* s1   = (const float*)d_in[0];
    const float* s2   = (const float*)d_in[1];
    const float* kern = (const float*)d_in[2];
    float* out = (float*)d_out;
    float* ws  = (float*)d_ws;

    float* n1    = ws;
    float* invn2 = ws + 16384;
    float* t     = ws + 32768;
    float* G     = ws + 36864;
    float* mav   = ws + 1085440;

    // zero t (4096) + G (1048576) — contiguous region
    hipMemsetAsync(t, 0, (size_t)(4096 + 1048576) * sizeof(float), stream);

    k_norms<<<8192, 256, 0, stream>>>(s1, s2, n1, invn2);
    k_t<<<512, 256, 0, stream>>>(s2, invn2, t);
    k_gram<<<2048, 256, 0, stream>>>(s2, invn2, G);
    k_mav<<<1024, 256, 0, stream>>>(s1, G, t, n1, mav);
    k_out<<<4096, 256, 0, stream>>>(s1, mav, kern, out);
}

// Round 3
// 177.927 us; speedup vs baseline: 1.4553x; 1.4553x over previous
//
#include <hip/hip_runtime.h>
#include <math.h>

#define EPS 1e-7f

constexpr int B = 16, L = 1024, D = 256, P = 20;
constexpr int LD = L * D;     // 262144
constexpr int DD = D * D;     // 65536

// ---------------------------------------------------------------------------
// ws layout (floats):
//   n1    : [B*L]       @ 0        (16384)
//   invn2 : [B*L]       @ 16384    (16384)
//   t     : [B*D]       @ 32768    (4096)   -- zeroed, atomic-accumulated
//   G     : [B*D*D]     @ 36864    (1048576)
//   Gp    : [4][B*D*D]  @ 1085440  (4194304) -- K-split partials, plain stores
//   mav   : [B*L*D]     @ 5279744  (4194304)
// total 9474048 floats = 37.9 MB
// ---------------------------------------------------------------------------

// K1: per-row L2 norms. n1 stored plain, n2 stored as reciprocal.
__global__ __launch_bounds__(256) void k_norms(const float* __restrict__ s1,
                                               const float* __restrict__ s2,
                                               float* __restrict__ n1,
                                               float* __restrict__ invn2) {
    int tid  = threadIdx.x;
    int lane = tid & 63, w = tid >> 6;
    int row  = blockIdx.x * 4 + w;            // 0..32767
    int r    = (row < B * L) ? row : row - B * L;
    const float* src = (row < B * L) ? s1 : s2;
    float4 v = *(const float4*)(src + (size_t)r * D + lane * 4);
    float s = v.x * v.x + v.y * v.y + v.z * v.z + v.w * v.w;
#pragma unroll
    for (int o = 32; o; o >>= 1) s += __shfl_down(s, o);
    if (lane == 0) {
        float n = sqrtf(fmaxf(s, EPS));
        if (row < B * L) n1[r] = n;
        else             invn2[r] = 1.0f / n;
    }
}

// K2: t[b,d] = sum_m s2[b,m,d] * invn2[b,m].  Grid: 16 b x 32 m-chunks.
// Atomics on t only: 131K lane-atomics total — negligible.
__global__ __launch_bounds__(256) void k_t(const float* __restrict__ s2,
                                           const float* __restrict__ invn2,
                                           float* __restrict__ t) {
    int b  = blockIdx.x >> 5;
    int mc = blockIdx.x & 31;                 // 32 m per chunk
    int d  = threadIdx.x;
    const float* sp = s2 + (size_t)b * LD + (size_t)mc * 32 * D + d;
    const float* wp = invn2 + b * L + mc * 32;
    float acc = 0.f;
#pragma unroll 4
    for (int m = 0; m < 32; ++m) acc += sp[(size_t)m * D] * wp[m];
    atomicAdd(&t[b * D + d], acc);
}

// K3: Gp[kc][b] = S2_chunk^T diag(invn2) S2_chunk over m in [kc*256, kc*256+256).
// 64x64 tile, 4x4/thread, depth-32 staging, NO atomics (plain float4 stores).
// Grid: 16 b x (4 ti x 4 tj x 4 kc) = 1024.
__global__ __launch_bounds__(256) void k_gram(const float* __restrict__ s2,
                                              const float* __restrict__ invn2,
                                              float* __restrict__ Gp) {
    __shared__ float As[32][68];   // scaled rows (output-row operand)
    __shared__ float Bs[32][68];
    int tid = threadIdx.x;
    int b   = blockIdx.x >> 6;
    int rem = blockIdx.x & 63;
    int ti  = rem >> 4;
    int tj  = (rem >> 2) & 3;
    int kc  = rem & 3;
    int tx  = tid & 15, ty = tid >> 4;
    int m0  = kc * 256;

    float acc[4][4];
#pragma unroll
    for (int i = 0; i < 4; ++i)
#pragma unroll
        for (int j = 0; j < 4; ++j) acc[i][j] = 0.f;

    int sr = tid >> 3;                 // staging row 0..31
    int sc = (tid & 7) * 4;            // staging col (floats), dense 128B/row segment
    for (int mc = 0; mc < 8; ++mc) {
        int mbase = m0 + mc * 32;
        __syncthreads();
        {
            int r = mbase + sr;
            float w = invn2[b * L + r];
            const float* base = s2 + (size_t)b * LD + (size_t)r * D;
            float4 va0 = *(const float4*)(base + ti * 64 + sc);
            float4 va1 = *(const float4*)(base + ti * 64 + sc + 32);
            float4 vb0 = *(const float4*)(base + tj * 64 + sc);
            float4 vb1 = *(const float4*)(base + tj * 64 + sc + 32);
            float4 s0; s0.x = va0.x * w; s0.y = va0.y * w; s0.z = va0.z * w; s0.w = va0.w * w;
            float4 s1v; s1v.x = va1.x * w; s1v.y = va1.y * w; s1v.z = va1.z * w; s1v.w = va1.w * w;
            *(float4*)&As[sr][sc]      = s0;
            *(float4*)&As[sr][sc + 32] = s1v;
            *(float4*)&Bs[sr][sc]      = vb0;
            *(float4*)&Bs[sr][sc + 32] = vb1;
        }
        __syncthreads();
#pragma unroll
        for (int k = 0; k < 32; ++k) {
            float4 a4 = *(const float4*)&As[k][ty * 4];   // 16-lane broadcast: free
            float4 b4 = *(const float4*)&Bs[k][tx * 4];   // 2-way alias: free
            float a[4] = {a4.x, a4.y, a4.z, a4.w};
            float bb[4] = {b4.x, b4.y, b4.z, b4.w};
#pragma unroll
            for (int i = 0; i < 4; ++i)
#pragma unroll
                for (int j = 0; j < 4; ++j) acc[i][j] += a[i] * bb[j];
        }
    }
    float* gp = Gp + ((size_t)kc * B + b) * DD +
                (size_t)(ti * 64 + ty * 4) * D + tj * 64 + tx * 4;
#pragma unroll
    for (int i = 0; i < 4; ++i) {
        float4 o;
        o.x = acc[i][0]; o.y = acc[i][1]; o.z = acc[i][2]; o.w = acc[i][3];
        *(float4*)(gp + (size_t)i * D) = o;
    }
}

// K3b: G = sum of 4 partials.  1024 blocks x 256 threads x 1 float4.
__global__ __launch_bounds__(256) void k_reduce(const float* __restrict__ Gp,
                                                float* __restrict__ G) {
    size_t i = ((size_t)blockIdx.x * 256 + threadIdx.x) * 4;
    float4 a = *(const float4*)(Gp + i);
    float4 b = *(const float4*)(Gp + (size_t)B * DD + i);
    float4 c = *(const float4*)(Gp + (size_t)2 * B * DD + i);
    float4 d = *(const float4*)(Gp + (size_t)3 * B * DD + i);
    float4 o;
    o.x = a.x + b.x + c.x + d.x;
    o.y = a.y + b.y + c.y + d.y;
    o.z = a.z + b.z + c.z + d.z;
    o.w = a.w + b.w + c.w + d.w;
    *(float4*)(G + i) = o;
}

// K4: u = s1 @ G (per batch), fused U = s1 . t, epilogue mav = u/(U + EPS*n1).
// 64x64 tiles, 4x4/thread, depth-32 staging.  Grid: 16 b x 16 lt x 4 nt = 1024.
__global__ __launch_bounds__(256) void k_mav(const float* __restrict__ s1,
                                             const float* __restrict__ G,
                                             const float* __restrict__ t,
                                             const float* __restrict__ n1,
                                             float* __restrict__ mav) {
    __shared__ float As[32][68];   // transposed s1 chunk: As[k][l]
    __shared__ float Bs[32][68];   // G chunk: Bs[k][n]
    __shared__ float ts[32];
    int tid = threadIdx.x;
    int b   = blockIdx.x >> 6;
    int rem = blockIdx.x & 63;
    int lt  = rem >> 2, nt = rem & 3;
    int l0  = lt * 64, n0 = nt * 64;
    int tx  = tid & 15, ty = tid >> 4;

    float acc[4][4];
    float Ua[4];
#pragma unroll
    for (int i = 0; i < 4; ++i) {
        Ua[i] = 0.f;
#pragma unroll
        for (int j = 0; j < 4; ++j) acc[i][j] = 0.f;
    }

    int al = tid >> 2;                 // A-staging: l row 0..63
    int ak = (tid & 3) * 8;            // A-staging: k offset 0,8,16,24
    int br = tid >> 3;                 // B-staging: k row 0..31
    int bc = (tid & 7) * 4;            // B-staging: col
    for (int kc = 0; kc < 8; ++kc) {
        int k0 = kc * 32;
        __syncthreads();
        {
            // stage A (transpose): s1[l0+al][k0+ak .. +7] -> As[k][al]
            const float* ap = s1 + (size_t)b * LD + (size_t)(l0 + al) * D + k0 + ak;
            float4 v0 = *(const float4*)ap;
            float4 v1 = *(const float4*)(ap + 4);
            As[ak + 0][al] = v0.x; As[ak + 1][al] = v0.y;
            As[ak + 2][al] = v0.z; As[ak + 3][al] = v0.w;
            As[ak + 4][al] = v1.x; As[ak + 5][al] = v1.y;
            As[ak + 6][al] = v1.z; As[ak + 7][al] = v1.w;
            // stage B: G[k0+br][n0 + bc .. / +32]
            const float* gpb = G + (size_t)b * DD + (size_t)(k0 + br) * D + n0;
            *(float4*)&Bs[br][bc]      = *(const float4*)(gpb + bc);
            *(float4*)&Bs[br][bc + 32] = *(const float4*)(gpb + bc + 32);
            if (tid < 32) ts[tid] = t[b * D + k0 + tid];
        }
        __syncthreads();
#pragma unroll
        for (int k = 0; k < 32; ++k) {
            float4 a4 = *(const float4*)&As[k][ty * 4];
            float4 b4 = *(const float4*)&Bs[k][tx * 4];
            float tk = ts[k];
            float a[4] = {a4.x, a4.y, a4.z, a4.w};
            float bb[4] = {b4.x, b4.y, b4.z, b4.w};
#pragma unroll
            for (int i = 0; i < 4; ++i) {
                Ua[i] += a[i] * tk;
#pragma unroll
                for (int j = 0; j < 4; ++j) acc[i][j] += a[i] * bb[j];
            }
        }
    }
#pragma unroll
    for (int i = 0; i < 4; ++i) {
        int l = l0 + ty * 4 + i;
        float n1v = n1[b * L + l];
        float inv = 1.0f / (Ua[i] + EPS * n1v);
        float4 o;
        o.x = acc[i][0] * inv; o.y = acc[i][1] * inv;
        o.z = acc[i][2] * inv; o.w = acc[i][3] * inv;
        *(float4*)(mav + (size_t)(b * L + l) * D + n0 + tx * 4) = o;
    }
}

// K5: out[b,l,p] = num / nv1 / nv2 over k2 = kernel^2.  One wave per row.
__global__ __launch_bounds__(256) void k_out(const float* __restrict__ s1,
                                             const float* __restrict__ mav,
                                             const float* __restrict__ kern,
                                             float* __restrict__ out) {
    __shared__ float k2s[P * D];   // 20 KB
    int tid = threadIdx.x;
#pragma unroll
    for (int p = 0; p < P; ++p) {
        float v = kern[p * D + tid];
        k2s[p * D + tid] = v * v;
    }
    __syncthreads();

    int w = tid >> 6, lane = tid & 63;
    int row = blockIdx.x * 4 + w;             // 0..16383
    int dg = lane & 15, ps = lane >> 4;

    const float* s1p = s1 + (size_t)row * D + dg * 4;
    const float* mvp = mav + (size_t)row * D + dg * 4;
    float4 sm[4], ss[4], mm[4];
#pragma unroll
    for (int j = 0; j < 4; ++j) {
        float4 sv = *(const float4*)(s1p + j * 64);
        float4 mv = *(const float4*)(mvp + j * 64);
        sm[j].x = sv.x * mv.x; sm[j].y = sv.y * mv.y; sm[j].z = sv.z * mv.z; sm[j].w = sv.w * mv.w;
        ss[j].x = sv.x * sv.x; ss[j].y = sv.y * sv.y; ss[j].z = sv.z * sv.z; ss[j].w = sv.w * sv.w;
        mm[j].x = mv.x * mv.x; mm[j].y = mv.y * mv.y; mm[j].z = mv.z * mv.z; mm[j].w = mv.w * mv.w;
    }
#pragma unroll
    for (int tI = 0; tI < 5; ++tI) {
        int p = ps + tI * 4;                  // 0..19
        float na = 0.f, nb = 0.f, nc = 0.f;
#pragma unroll
        for (int j = 0; j < 4; ++j) {
            float4 kv = *(const float4*)&k2s[p * D + j * 64 + dg * 4];
            na += sm[j].x * kv.x + sm[j].y * kv.y + sm[j].z * kv.z + sm[j].w * kv.w;
            nb += ss[j].x * kv.x + ss[j].y * kv.y + ss[j].z * kv.z + ss[j].w * kv.w;
            nc += mm[j].x * kv.x + mm[j].y * kv.y + mm[j].z * kv.z + mm[j].w * kv.w;
        }
#pragma unroll
        for (int o = 8; o; o >>= 1) {
            na += __shfl_down(na, o, 16);
            nb += __shfl_down(nb, o, 16);
            nc += __shfl_down(nc, o, 16);
        }
        if (dg == 0) {
            float d1 = sqrtf(fmaxf(nb, EPS));
            float d2 = sqrtf(fmaxf(nc, EPS));
            out[row * P + p] = na / d1 / d2;
        }
    }
}

extern "C" void kernel_launch(void* const* d_in, const int* in_sizes, int n_in,
                              void* d_out, int out_size, void* d_ws, size_t ws_size,
                              hipStream_t stream) {
    const float* s1   = (const float*)d_in[0];
    const float* s2   = (const float*)d_in[1];
    const float* kern = (const float*)d_in[2];
    float* out = (float*)d_out;
    float* ws  = (float*)d_ws;

    float* n1    = ws;
    float* invn2 = ws + 16384;
    float* t     = ws + 32768;
    float* G     = ws + 36864;
    float* Gp    = ws + 1085440;
    float* mav   = ws + 5279744;

    // zero t only (16 KB) — G is written with plain stores now
    hipMemsetAsync(t, 0, (size_t)4096 * sizeof(float), stream);

    k_norms<<<8192, 256, 0, stream>>>(s1, s2, n1, invn2);
    k_t<<<512, 256, 0, stream>>>(s2, invn2, t);
    k_gram<<<1024, 256, 0, stream>>>(s2, invn2, Gp);
    k_reduce<<<1024, 256, 0, stream>>>(Gp, G);
    k_mav<<<1024, 256, 0, stream>>>(s1, G, t, n1, mav);
    k_out<<<4096, 256, 0, stream>>>(s1, mav, kern, out);
}

// Round 4
// 164.197 us; speedup vs baseline: 1.5770x; 1.0836x over previous
//
#include <hip/hip_runtime.h>
#include <math.h>

#define EPS 1e-7f

constexpr int B = 16, L = 1024, D = 256, P = 20;
constexpr int LD = L * D;     // 262144
constexpr int DD = D * D;     // 65536

typedef __attribute__((ext_vector_type(8))) short bf16x8;
typedef __attribute__((ext_vector_type(4))) float f32x4;

// ---------------------------------------------------------------------------
// ws layout (float slots):
//   n1    @0         16384      fp32 [B*L]
//   invn2 @16384     16384      fp32 [B*L]
//   t     @32768     4096       fp32 [B*D]  (memset 0, atomic)
//   invU  @36864     16384      fp32 [B*L]  1/(s1.t + eps*n1)
//   s1h   @53248     2097152    bf16 [B*L][D]      (hi split of s1)
//   s1l   @2150400   2097152    bf16 [B*L][D]      (lo split)
//   AhT   @4247552   2097152    bf16 [B][D][L]     (scaled s2, transposed, hi)
//   AlT   @6344704   2097152    bf16 [B][D][L]     (scaled s2, transposed, lo)
//   BhT   @8441856   2097152    bf16 [B][D][L]     (s2 transposed, hi)
//   BlT   @10539008  2097152    bf16 [B][D][L]     (s2 transposed, lo)
//   Gh    @12636160  524288     bf16 [B][D][D]
//   Gl    @13160448  524288     bf16 [B][D][D]
//   Gp    @13684736  4194304    fp32 [4][B][D][D]  gram K-split partials
//   mav   @17879040  4194304    fp32 [B*L][D]
// total 22073344 floats = 84.2 MB
// ---------------------------------------------------------------------------

__device__ inline void bf16split(float x, unsigned short &h, unsigned short &l) {
    union { float f; unsigned u; } a; a.f = x;
    unsigned hu = (a.u + 0x7FFFu + ((a.u >> 16) & 1u)) & 0xFFFF0000u;
    union { unsigned u; float f; } hb; hb.u = hu;
    h = (unsigned short)(hu >> 16);
    float r = x - hb.f;
    union { float f; unsigned u; } c; c.f = r;
    l = (unsigned short)((c.u + 0x7FFFu + ((c.u >> 16) & 1u)) >> 16);
}

// K1: per-row L2 norms; also emits bf16 hi/lo split of s1 (natural layout).
__global__ __launch_bounds__(256) void k_norms(const float* __restrict__ s1,
                                               const float* __restrict__ s2,
                                               float* __restrict__ n1,
                                               float* __restrict__ invn2,
                                               unsigned short* __restrict__ s1h,
                                               unsigned short* __restrict__ s1l) {
    int tid  = threadIdx.x;
    int lane = tid & 63, w = tid >> 6;
    int row  = blockIdx.x * 4 + w;            // 0..32767
    int r    = (row < B * L) ? row : row - B * L;
    const float* src = (row < B * L) ? s1 : s2;
    float4 v = *(const float4*)(src + (size_t)r * D + lane * 4);
    float s = v.x * v.x + v.y * v.y + v.z * v.z + v.w * v.w;
#pragma unroll
    for (int o = 32; o; o >>= 1) s += __shfl_down(s, o);
    if (row < B * L) {
        ushort4 h4, l4;
        bf16split(v.x, h4.x, l4.x);
        bf16split(v.y, h4.y, l4.y);
        bf16split(v.z, h4.z, l4.z);
        bf16split(v.w, h4.w, l4.w);
        *(ushort4*)(s1h + (size_t)r * D + lane * 4) = h4;
        *(ushort4*)(s1l + (size_t)r * D + lane * 4) = l4;
    }
    if (lane == 0) {
        float n = sqrtf(fmaxf(s, EPS));
        if (row < B * L) n1[r] = n;
        else             invn2[r] = 1.0f / n;
    }
}

// K2: t[b,d] = sum_m s2[b,m,d] * invn2[b,m].
__global__ __launch_bounds__(256) void k_t(const float* __restrict__ s2,
                                           const float* __restrict__ invn2,
                                           float* __restrict__ t) {
    int b  = blockIdx.x >> 5;
    int mc = blockIdx.x & 31;
    int d  = threadIdx.x;
    const float* sp = s2 + (size_t)b * LD + (size_t)mc * 32 * D + d;
    const float* wp = invn2 + b * L + mc * 32;
    float acc = 0.f;
#pragma unroll 4
    for (int m = 0; m < 32; ++m) acc += sp[(size_t)m * D] * wp[m];
    atomicAdd(&t[b * D + d], acc);
}

// K2b: invU[b,l] = 1/(s1[l].t[b] + eps*n1[l])   (exact fp32 path for S)
__global__ __launch_bounds__(256) void k_u(const float* __restrict__ s1,
                                           const float* __restrict__ t,
                                           const float* __restrict__ n1,
                                           float* __restrict__ invU) {
    int tid  = threadIdx.x;
    int lane = tid & 63, w = tid >> 6;
    int row  = blockIdx.x * 4 + w;            // 0..16383
    int b    = row >> 10;
    float4 v = *(const float4*)(s1 + (size_t)row * D + lane * 4);
    float4 tv = *(const float4*)(t + b * D + lane * 4);
    float s = v.x * tv.x + v.y * tv.y + v.z * tv.z + v.w * tv.w;
#pragma unroll
    for (int o = 32; o; o >>= 1) s += __shfl_down(s, o);
    if (lane == 0) invU[row] = 1.0f / (s + EPS * n1[row]);
}

// K3: transpose+split s2 -> AhT/AlT (invn2-scaled) and BhT/BlT (unscaled),
// all [B][D][L] bf16 (K=m contiguous).  64x64 LDS tile per block.
__global__ __launch_bounds__(256) void k_split2(const float* __restrict__ s2,
                                                const float* __restrict__ invn2,
                                                unsigned short* __restrict__ AhT,
                                                unsigned short* __restrict__ AlT,
                                                unsigned short* __restrict__ BhT,
                                                unsigned short* __restrict__ BlT) {
    __shared__ float tile[64][65];
    __shared__ float wsh[64];
    int tid = threadIdx.x;
    int b   = blockIdx.x >> 6;
    int rem = blockIdx.x & 63;
    int mt  = rem >> 2, dt = rem & 3;
    int m0  = mt * 64, d0 = dt * 64;
    {
        int r = tid >> 2, cs = (tid & 3) * 16;
        const float* gp = s2 + (size_t)b * LD + (size_t)(m0 + r) * D + d0 + cs;
        float4 v0 = ((const float4*)gp)[0];
        float4 v1 = ((const float4*)gp)[1];
        float4 v2 = ((const float4*)gp)[2];
        float4 v3 = ((const float4*)gp)[3];
        *(float4*)&tile[r][cs]      = v0;
        *(float4*)&tile[r][cs + 4]  = v1;
        *(float4*)&tile[r][cs + 8]  = v2;
        *(float4*)&tile[r][cs + 12] = v3;
        if (tid < 64) wsh[tid] = invn2[b * L + m0 + tid];
    }
    __syncthreads();
    int dc = tid >> 2, ms = (tid & 3) * 16;
    union { unsigned short us[16]; uint4 q[2]; } pAh, pAl, pBh, pBl;
#pragma unroll
    for (int k = 0; k < 16; ++k) {
        int m = ms + k;
        float v = tile[m][dc];
        float wv = v * wsh[m];
        bf16split(v,  pBh.us[k], pBl.us[k]);
        bf16split(wv, pAh.us[k], pAl.us[k]);
    }
    size_t o = (size_t)b * LD + (size_t)(d0 + dc) * L + m0 + ms;
    *(uint4*)(AhT + o) = pAh.q[0]; *(uint4*)(AhT + o + 8) = pAh.q[1];
    *(uint4*)(AlT + o) = pAl.q[0]; *(uint4*)(AlT + o + 8) = pAl.q[1];
    *(uint4*)(BhT + o) = pBh.q[0]; *(uint4*)(BhT + o + 8) = pBh.q[1];
    *(uint4*)(BlT + o) = pBl.q[0]; *(uint4*)(BlT + o + 8) = pBl.q[1];
}

// K4: Gram via MFMA.  G = Ah'Bh + Ah'Bl + Al'Bh (bf16x2 emulation), K-split x4.
// Block: 128x128 output tile, 4 waves 2x2, wave = 64x64 = 4x4 MFMA 16x16x32.
// Grid: 16 b x 2 ti x 2 tj x 4 kc = 256.
__global__ __launch_bounds__(256) void k_gram_mfma(const unsigned short* __restrict__ AhT,
                                                   const unsigned short* __restrict__ AlT,
                                                   const unsigned short* __restrict__ BhT,
                                                   const unsigned short* __restrict__ BlT,
                                                   float* __restrict__ Gp) {
    __shared__ short As[128 * 72];
    __shared__ short Bs[128 * 72];
    int tid  = threadIdx.x;
    int b    = blockIdx.x >> 4;
    int rem  = blockIdx.x & 15;
    int ti   = rem >> 3, tj = (rem >> 2) & 1, kc = rem & 3;
    int wave = tid >> 6, lane = tid & 63;
    int wr   = (wave >> 1) * 64, wc = (wave & 1) * 64;
    int lr   = lane & 15, lq = lane >> 4;
    int srow = tid >> 1, shalf = (tid & 1) * 32;

    f32x4 acc[4][4];
#pragma unroll
    for (int i = 0; i < 4; ++i)
#pragma unroll
        for (int j = 0; j < 4; ++j) acc[i][j] = (f32x4){0.f, 0.f, 0.f, 0.f};

#pragma unroll 1
    for (int tau = 0; tau < 3; ++tau) {
        const unsigned short* Ap = (tau < 2) ? AhT : AlT;
        const unsigned short* Bp = (tau == 1) ? BlT : BhT;
#pragma unroll 1
        for (int kb = 0; kb < 4; ++kb) {
            int koff = kc * 256 + kb * 64 + shalf;
            __syncthreads();
            {
                const unsigned short* ga = Ap + (size_t)b * LD + (size_t)(ti * 128 + srow) * L + koff;
                const unsigned short* gb = Bp + (size_t)b * LD + (size_t)(tj * 128 + srow) * L + koff;
                uint4 a0 = ((const uint4*)ga)[0], a1 = ((const uint4*)ga)[1];
                uint4 a2 = ((const uint4*)ga)[2], a3 = ((const uint4*)ga)[3];
                uint4 b0 = ((const uint4*)gb)[0], b1 = ((const uint4*)gb)[1];
                uint4 b2 = ((const uint4*)gb)[2], b3 = ((const uint4*)gb)[3];
                short* la = &As[srow * 72 + shalf];
                short* lb = &Bs[srow * 72 + shalf];
                ((uint4*)la)[0] = a0; ((uint4*)la)[1] = a1;
                ((uint4*)la)[2] = a2; ((uint4*)la)[3] = a3;
                ((uint4*)lb)[0] = b0; ((uint4*)lb)[1] = b1;
                ((uint4*)lb)[2] = b2; ((uint4*)lb)[3] = b3;
            }
            __syncthreads();
#pragma unroll
            for (int ks = 0; ks < 2; ++ks) {
                bf16x8 af[4], bfr[4];
#pragma unroll
                for (int i = 0; i < 4; ++i)
                    af[i] = *(const bf16x8*)&As[(wr + i * 16 + lr) * 72 + ks * 32 + lq * 8];
#pragma unroll
                for (int j = 0; j < 4; ++j)
                    bfr[j] = *(const bf16x8*)&Bs[(wc + j * 16 + lr) * 72 + ks * 32 + lq * 8];
#pragma unroll
                for (int i = 0; i < 4; ++i)
#pragma unroll
                    for (int j = 0; j < 4; ++j)
                        acc[i][j] = __builtin_amdgcn_mfma_f32_16x16x32_bf16(af[i], bfr[j], acc[i][j], 0, 0, 0);
            }
        }
    }
    float* gout = Gp + ((size_t)(kc * B + b)) * DD;
#pragma unroll
    for (int i = 0; i < 4; ++i) {
#pragma unroll
        for (int r = 0; r < 4; ++r) {
            int row = ti * 128 + wr + i * 16 + lq * 4 + r;
#pragma unroll
            for (int j = 0; j < 4; ++j) {
                int col = tj * 128 + wc + j * 16 + lr;
                gout[(size_t)row * D + col] = acc[i][j][r];
            }
        }
    }
}

// K5: reduce 4 gram partials; emit bf16 hi/lo split of G (still symmetric).
__global__ __launch_bounds__(256) void k_reduceG(const float* __restrict__ Gp,
                                                 unsigned short* __restrict__ Gh,
                                                 unsigned short* __restrict__ Gl) {
    size_t i = ((size_t)blockIdx.x * 256 + threadIdx.x) * 4;
    float4 a = *(const float4*)(Gp + i);
    float4 b = *(const float4*)(Gp + (size_t)B * DD + i);
    float4 c = *(const float4*)(Gp + (size_t)2 * B * DD + i);
    float4 d = *(const float4*)(Gp + (size_t)3 * B * DD + i);
    float4 s;
    s.x = a.x + b.x + c.x + d.x;
    s.y = a.y + b.y + c.y + d.y;
    s.z = a.z + b.z + c.z + d.z;
    s.w = a.w + b.w + c.w + d.w;
    ushort4 h4, l4;
    bf16split(s.x, h4.x, l4.x);
    bf16split(s.y, h4.y, l4.y);
    bf16split(s.z, h4.z, l4.z);
    bf16split(s.w, h4.w, l4.w);
    *(ushort4*)(Gh + i) = h4;
    *(ushort4*)(Gl + i) = l4;
}

// K6: mav = (s1 @ G) * invU via MFMA (bf16x2: s1h*Gh + s1h*Gl + s1l*Gh).
// B-operand tiles read G rows directly (G symmetric => already K-contiguous).
// Block: 128(l) x 128(n), grid: 16 b x 8 lt x 2 nt = 256.
__global__ __launch_bounds__(256) void k_mav_mfma(const unsigned short* __restrict__ s1h,
                                                  const unsigned short* __restrict__ s1l,
                                                  const unsigned short* __restrict__ Gh,
                                                  const unsigned short* __restrict__ Gl,
                                                  const float* __restrict__ invU,
                                                  float* __restrict__ mav) {
    __shared__ short As[128 * 72];
    __shared__ short Bs[128 * 72];
    int tid  = threadIdx.x;
    int b    = blockIdx.x >> 4;
    int rem  = blockIdx.x & 15;
    int lt   = rem >> 1, nt = rem & 1;
    int l0   = lt * 128, n0 = nt * 128;
    int wave = tid >> 6, lane = tid & 63;
    int wr   = (wave >> 1) * 64, wc = (wave & 1) * 64;
    int lr   = lane & 15, lq = lane >> 4;
    int srow = tid >> 1, shalf = (tid & 1) * 32;

    f32x4 acc[4][4];
#pragma unroll
    for (int i = 0; i < 4; ++i)
#pragma unroll
        for (int j = 0; j < 4; ++j) acc[i][j] = (f32x4){0.f, 0.f, 0.f, 0.f};

#pragma unroll 1
    for (int tau = 0; tau < 3; ++tau) {
        const unsigned short* Ap = (tau < 2) ? s1h : s1l;
        const unsigned short* Bp = (tau == 1) ? Gl : Gh;
#pragma unroll 1
        for (int kb = 0; kb < 4; ++kb) {
            int koff = kb * 64 + shalf;
            __syncthreads();
            {
                const unsigned short* ga = Ap + (size_t)(b * L + l0 + srow) * D + koff;
                const unsigned short* gb = Bp + (size_t)b * DD + (size_t)(n0 + srow) * D + koff;
                uint4 a0 = ((const uint4*)ga)[0], a1 = ((const uint4*)ga)[1];
                uint4 a2 = ((const uint4*)ga)[2], a3 = ((const uint4*)ga)[3];
                uint4 b0 = ((const uint4*)gb)[0], b1 = ((const uint4*)gb)[1];
                uint4 b2 = ((const uint4*)gb)[2], b3 = ((const uint4*)gb)[3];
                short* la = &As[srow * 72 + shalf];
                short* lb = &Bs[srow * 72 + shalf];
                ((uint4*)la)[0] = a0; ((uint4*)la)[1] = a1;
                ((uint4*)la)[2] = a2; ((uint4*)la)[3] = a3;
                ((uint4*)lb)[0] = b0; ((uint4*)lb)[1] = b1;
                ((uint4*)lb)[2] = b2; ((uint4*)lb)[3] = b3;
            }
            __syncthreads();
#pragma unroll
            for (int ks = 0; ks < 2; ++ks) {
                bf16x8 af[4], bfr[4];
#pragma unroll
                for (int i = 0; i < 4; ++i)
                    af[i] = *(const bf16x8*)&As[(wr + i * 16 + lr) * 72 + ks * 32 + lq * 8];
#pragma unroll
                for (int j = 0; j < 4; ++j)
                    bfr[j] = *(const bf16x8*)&Bs[(wc + j * 16 + lr) * 72 + ks * 32 + lq * 8];
#pragma unroll
                for (int i = 0; i < 4; ++i)
#pragma unroll
                    for (int j = 0; j < 4; ++j)
                        acc[i][j] = __builtin_amdgcn_mfma_f32_16x16x32_bf16(af[i], bfr[j], acc[i][j], 0, 0, 0);
            }
        }
    }
#pragma unroll
    for (int i = 0; i < 4; ++i) {
#pragma unroll
        for (int r = 0; r < 4; ++r) {
            int l  = l0 + wr + i * 16 + lq * 4 + r;
            float iv = invU[b * L + l];
#pragma unroll
            for (int j = 0; j < 4; ++j) {
                int col = n0 + wc + j * 16 + lr;
                mav[(size_t)(b * L + l) * D + col] = acc[i][j][r] * iv;
            }
        }
    }
}

// K7: out[b,l,p] = num / nv1 / nv2 over k2 = kernel^2.  One wave per row.
__global__ __launch_bounds__(256) void k_out(const float* __restrict__ s1,
                                             const float* __restrict__ mav,
                                             const float* __restrict__ kern,
                                             float* __restrict__ out) {
    __shared__ float k2s[P * D];
    int tid = threadIdx.x;
#pragma unroll
    for (int p = 0; p < P; ++p) {
        float v = kern[p * D + tid];
        k2s[p * D + tid] = v * v;
    }
    __syncthreads();

    int w = tid >> 6, lane = tid & 63;
    int row = blockIdx.x * 4 + w;
    int dg = lane & 15, ps = lane >> 4;

    const float* s1p = s1 + (size_t)row * D + dg * 4;
    const float* mvp = mav + (size_t)row * D + dg * 4;
    float4 sm[4], ss[4], mm[4];
#pragma unroll
    for (int j = 0; j < 4; ++j) {
        float4 sv = *(const float4*)(s1p + j * 64);
        float4 mv = *(const float4*)(mvp + j * 64);
        sm[j].x = sv.x * mv.x; sm[j].y = sv.y * mv.y; sm[j].z = sv.z * mv.z; sm[j].w = sv.w * mv.w;
        ss[j].x = sv.x * sv.x; ss[j].y = sv.y * sv.y; ss[j].z = sv.z * sv.z; ss[j].w = sv.w * sv.w;
        mm[j].x = mv.x * mv.x; mm[j].y = mv.y * mv.y; mm[j].z = mv.z * mv.z; mm[j].w = mv.w * mv.w;
    }
#pragma unroll
    for (int tI = 0; tI < 5; ++tI) {
        int p = ps + tI * 4;
        float na = 0.f, nb = 0.f, nc = 0.f;
#pragma unroll
        for (int j = 0; j < 4; ++j) {
            float4 kv = *(const float4*)&k2s[p * D + j * 64 + dg * 4];
            na += sm[j].x * kv.x + sm[j].y * kv.y + sm[j].z * kv.z + sm[j].w * kv.w;
            nb += ss[j].x * kv.x + ss[j].y * kv.y + ss[j].z * kv.z + ss[j].w * kv.w;
            nc += mm[j].x * kv.x + mm[j].y * kv.y + mm[j].z * kv.z + mm[j].w * kv.w;
        }
#pragma unroll
        for (int o = 8; o; o >>= 1) {
            na += __shfl_down(na, o, 16);
            nb += __shfl_down(nb, o, 16);
            nc += __shfl_down(nc, o, 16);
        }
        if (dg == 0) {
            float d1 = sqrtf(fmaxf(nb, EPS));
            float d2 = sqrtf(fmaxf(nc, EPS));
            out[row * P + p] = na / d1 / d2;
        }
    }
}

extern "C" void kernel_launch(void* const* d_in, const int* in_sizes, int n_in,
                              void* d_out, int out_size, void* d_ws, size_t ws_size,
                              hipStream_t stream) {
    const float* s1   = (const float*)d_in[0];
    const float* s2   = (const float*)d_in[1];
    const float* kern = (const float*)d_in[2];
    float* out = (float*)d_out;
    float* ws  = (float*)d_ws;

    float* n1    = ws;
    float* invn2 = ws + 16384;
    float* t     = ws + 32768;
    float* invU  = ws + 36864;
    unsigned short* s1h = (unsigned short*)(ws + 53248);
    unsigned short* s1l = (unsigned short*)(ws + 2150400);
    unsigned short* AhT = (unsigned short*)(ws + 4247552);
    unsigned short* AlT = (unsigned short*)(ws + 6344704);
    unsigned short* BhT = (unsigned short*)(ws + 8441856);
    unsigned short* BlT = (unsigned short*)(ws + 10539008);
    unsigned short* Gh  = (unsigned short*)(ws + 12636160);
    unsigned short* Gl  = (unsigned short*)(ws + 13160448);
    float* Gp  = ws + 13684736;
    float* mav = ws + 17879040;

    hipMemsetAsync(t, 0, (size_t)4096 * sizeof(float), stream);

    k_norms<<<8192, 256, 0, stream>>>(s1, s2, n1, invn2, s1h, s1l);
    k_t<<<512, 256, 0, stream>>>(s2, invn2, t);
    k_u<<<4096, 256, 0, stream>>>(s1, t, n1, invU);
    k_split2<<<1024, 256, 0, stream>>>(s2, invn2, AhT, AlT, BhT, BlT);
    k_gram_mfma<<<256, 256, 0, stream>>>(AhT, AlT, BhT, BlT, Gp);
    k_reduceG<<<1024, 256, 0, stream>>>(Gp, Gh, Gl);
    k_mav_mfma<<<256, 256, 0, stream>>>(s1h, s1l, Gh, Gl, invU, mav);
    k_out<<<4096, 256, 0, stream>>>(s1, mav, kern, out);
}